// Round 13
// baseline (204.417 us; speedup 1.0000x reference)
//
#include <hip/hip_runtime.h>

#define KTOP 8
typedef unsigned short u16;
typedef unsigned int u32;
typedef short bf16x8 __attribute__((ext_vector_type(8)));   // 8 bf16 = 4 VGPR
typedef float f32x16 __attribute__((ext_vector_type(16)));  // 32x32 acc

// ---------- ws byte layout (need = 8M+64K, same as all passing rounds) ----------
// qh @0      : u16[2*64*4096]  1 MB   bf16-hi, [b][y][x*64 + (ch^((x&7)<<3))]
// kh @1M     : u16[...]        1 MB
// nk @2M (f32 8192), kk @2M+32K (f32 8192)
// cand @2M+64K : u32[2*4096*128]  4 MB   (16 subsets x 8 keys)  ends 6M+64K
// vT   @6M+64K : f32[2*4096*64]   2 MB   v transposed (optional)

__device__ __forceinline__ u16 f2bf(float x) {
  u32 u = __builtin_bit_cast(u32, x);
  u32 r = u + 0x7fffu + ((u >> 16) & 1u);
  return (u16)(r >> 16);
}
__device__ __forceinline__ float bf2f(u16 h) {
  u32 u = ((u32)h) << 16;
  return __builtin_bit_cast(float, u);
}
__device__ __forceinline__ u32 ordenc(float c) {
  u32 u = __builtin_bit_cast(u32, c);
  u32 s = (u32)((int)u >> 31);
  return u ^ (s | 0x80000000u);   // monotone float->uint
}
__device__ __forceinline__ u32 med3u(u32 a, u32 b, u32 c) {
  u32 d;
  asm("v_med3_u32 %0, %1, %2, %3" : "=v"(d) : "v"(a), "v"(b), "v"(c));
  return d;
}
// sorted-ascending top-8 insert: new[0]=min(a0,x), new[p]=med3(a[p-1],a[p],x).
__device__ __forceinline__ void kins(u32 (&k8)[KTOP], u32 x) {
  u32 n0 = k8[0] < x ? k8[0] : x;
#pragma unroll
  for (int p = KTOP - 1; p >= 1; --p) k8[p] = med3u(k8[p - 1], k8[p], x);
  k8[0] = n0;
}

// ---------------- kernel 1: transpose + bf16-hi (+ nk) + vT ----------------
__global__ void prep_kernel(const float* __restrict__ q, const float* __restrict__ k,
                            const float* __restrict__ v,
                            u16* __restrict__ qh, u16* __restrict__ kh,
                            float* __restrict__ vt, float* __restrict__ nk) {
  __shared__ float tile[64][65];
  int bid = blockIdx.x;
  int t = threadIdx.x;

  if (bid >= 256) {                       // ---- v transpose path ----
    int r = bid - 256;
    int b = r >> 6, y = r & 63;
    const float* src = v + (size_t)b * (64 * 4096) + (y << 6);
#pragma unroll
    for (int e = 0; e < 16; ++e) {
      int idx = e * 256 + t;
      int c = idx >> 6, x = idx & 63;
      tile[c][x] = src[(c << 12) + x];
    }
    __syncthreads();
    int x = t >> 2, cg = t & 3;
    float* dst = vt + ((size_t)b << 18) + (((y << 6) + x) << 6) + (cg << 4);
#pragma unroll
    for (int i4 = 0; i4 < 4; ++i4) {
      float4 w;
      w.x = tile[cg * 16 + i4 * 4 + 0][x];
      w.y = tile[cg * 16 + i4 * 4 + 1][x];
      w.z = tile[cg * 16 + i4 * 4 + 2][x];
      w.w = tile[cg * 16 + i4 * 4 + 3][x];
      *(float4*)&dst[i4 * 4] = w;
    }
    return;
  }

  int which = bid >> 7;
  int b = (bid >> 6) & 1;
  int y = bid & 63;
  const float* src = (which ? k : q) + (size_t)b * (64 * 4096) + (y << 6);
#pragma unroll
  for (int e = 0; e < 16; ++e) {
    int idx = e * 256 + t;
    int c = idx >> 6, x = idx & 63;
    tile[c][x] = src[(c << 12) + x];
  }
  __syncthreads();

  int x = t >> 2, cg = t & 3;
  u16 hi[16];
#pragma unroll
  for (int i = 0; i < 16; ++i) hi[i] = f2bf(tile[cg * 16 + i][x]);
  u16* dh = (which ? kh : qh) + ((size_t)(b * 64 + y) << 12);
  int sw = (x & 7) << 3;
#pragma unroll
  for (int cc = 0; cc < 2; ++cc) {
    int base = (x << 6) + ((cg * 16 + cc * 8) ^ sw);
    uint4 wh;
    wh.x = (u32)hi[cc*8+0] | ((u32)hi[cc*8+1] << 16);
    wh.y = (u32)hi[cc*8+2] | ((u32)hi[cc*8+3] << 16);
    wh.z = (u32)hi[cc*8+4] | ((u32)hi[cc*8+5] << 16);
    wh.w = (u32)hi[cc*8+6] | ((u32)hi[cc*8+7] << 16);
    *(uint4*)&dh[base] = wh;
  }
  if (which && t < 64) {
    float s = 0.f;
#pragma unroll
    for (int c = 0; c < 64; ++c) { float vv = tile[c][t]; s += vv * vv; }
    nk[(b << 12) + (y << 6) + t] = s;
  }
}

// ---------------- kernel 2: 3x3 zero-padded stencil -> kk ----------------
__global__ void kk_kernel(const float* __restrict__ nk, float* __restrict__ kk) {
  int p = blockIdx.x * blockDim.x + threadIdx.x;
  int b = p >> 12, pix = p & 4095;
  int y = pix >> 6, x = pix & 63;
  float s = 0.f;
#pragma unroll
  for (int di = -1; di <= 1; ++di)
#pragma unroll
    for (int dj = -1; dj <= 1; ++dj) {
      int yy = y + di, xx = x + dj;
      if ((unsigned)yy < 64u && (unsigned)xx < 64u)
        s += nk[(b << 12) + (yy << 6) + xx];
    }
  kk[p] = s;
}

// ---------------- kernel 3: ring + hi-only MFMA + bf16 S-tile + med3 top-8 ----------------
// 16th-split: 4 key rows/block. grid 1024 = b(2) x rowpair(32) x 16th(16).
// LDS 51.5 KB (ring 32K + bf16 Rb 18.5K + kkbuf 1K) -> 3 blocks/CU.
__launch_bounds__(512, 6)
__global__ void cost_topk_kernel(const u16* __restrict__ qh,
                                 const u16* __restrict__ kh,
                                 const float* __restrict__ kkg,
                                 u32* __restrict__ cand) {
  __shared__ __align__(16) u16 ring[4][4096];        // 32 KB, slot = row & 3
  __shared__ u16 Rb2[2 * 66 * 70];                   // 2 bordered bf16 S tiles
  __shared__ float kkbuf[256];                       // kk rows q0..q0+3

  int bid = blockIdx.x;
  int b   = bid >> 9;
  int rp  = (bid >> 4) & 31;
  int e16 = bid & 15;
  int q0  = e16 << 2;
  int iy0 = rp << 1;

  int t = threadIdx.x;
  int lane = t & 63;
  int wv = t >> 6;
  int h  = wv >> 2;
  int quad = wv & 3;
  int wr = quad >> 1, wc = quad & 1;
  int l31 = lane & 31, lk8 = (lane >> 5) << 3;
  int apix = (wr << 5) + l31;
  int bpix = (wc << 5) + l31;
  int sx = t & 63, sseg = (t >> 6) & 3, jxs = sseg << 4;
  int iy = iy0 + h;

  const u16* qhb = qh + ((size_t)b << 18);
  const u16* khb = kh + ((size_t)b << 18);

  const bf16x8 z8 = {0,0,0,0,0,0,0,0};
  const uint4 z4 = {0u,0u,0u,0u};

  // A fragments (hi only), rows iy-1..iy+1, direct global->VGPR
  bf16x8 qa[3][4];
  int swA = (apix & 7) << 3;
#pragma unroll
  for (int d = 0; d < 3; ++d) {
    int qy = iy - 1 + d;
    bool ok = (unsigned)qy < 64u;
    int rb = (qy & 63) << 12;
#pragma unroll
    for (int c4 = 0; c4 < 4; ++c4) {
      bf16x8 vv = *(const bf16x8*)&qhb[rb + (apix << 6) + (((c4 << 4) + lk8) ^ swA)];
      qa[d][c4] = ok ? vv : z8;
    }
  }

  // zero Rb (borders stay zero); stage kk rows; prefill ring rows q0-1..q0+1
  for (int i = t; i < 2 * 66 * 70; i += 512) Rb2[i] = 0;
  if (t < 256) kkbuf[t] = kkg[(b << 12) + (q0 << 6) + t];
#pragma unroll
  for (int d = 0; d < 3; ++d) {
    int r = q0 - 1 + d;
    bool ok = (unsigned)r < 64u;
    uint4 vv = ok ? *(const uint4*)&khb[((r & 63) << 12) + (t << 3)] : z4;
    *(uint4*)&ring[(r + 4) & 3][t << 3] = vv;
  }
  __syncthreads();

  u32 k8a[KTOP], k8b[KTOP];
#pragma unroll
  for (int s = 0; s < KTOP; ++s) { k8a[s] = 0xFFFFFFFFu; k8b[s] = 0xFFFFFFFFu; }

  int swB = (bpix & 7) << 3;
  u16* Rh = &Rb2[h * (66 * 70)];

  for (int jt = 0; jt < 4; ++jt) {
    int jy = q0 + jt;
    // prefetch next ring row (global->reg; LDS write after barrier)
    int pr = jy + 2;
    bool pok = (jt < 3) && (pr < 64);
    uint4 pf = pok ? *(const uint4*)&khb[((pr & 63) << 12) + (t << 3)] : z4;

    // ---- MFMA: two independent acc chains + setprio ----
    f32x16 acc0, acc1;
#pragma unroll
    for (int i = 0; i < 16; ++i) { acc0[i] = 0.f; acc1[i] = 0.f; }
    __builtin_amdgcn_s_setprio(1);
#pragma unroll
    for (int d = 0; d < 3; ++d) {
      const u16* rg = ring[(jy - 1 + d) & 3];
#pragma unroll
      for (int c4 = 0; c4 < 4; ++c4) {
        bf16x8 bh = *(const bf16x8*)&rg[(bpix << 6) + (((c4 << 4) + lk8) ^ swB)];
        if ((d ^ c4) & 1)
          acc1 = __builtin_amdgcn_mfma_f32_32x32x16_bf16(qa[d][c4], bh, acc1, 0, 0, 0);
        else
          acc0 = __builtin_amdgcn_mfma_f32_32x32x16_bf16(qa[d][c4], bh, acc0, 0, 0, 0);
      }
    }
    __builtin_amdgcn_s_setprio(0);
    __syncthreads();   // prev stencil reads of Rb done (ring write slot disjoint)

    // C-write (col=lane&31, row=(r&3)+8*(r>>2)+4*(lane>>5)) as bf16
#pragma unroll
    for (int r = 0; r < 16; ++r) {
      int row = (wr << 5) + (r & 3) + ((r >> 2) << 3) + ((lane >> 5) << 2);
      u32 u = __builtin_bit_cast(u32, acc0[r] + acc1[r]);
      Rh[(row + 1) * 70 + (wc << 5) + l31 + 1] = (u16)((u + 0x8000u) >> 16);
    }
    if (jt < 3) *(uint4*)&ring[pr & 3][t << 3] = pf;
    __syncthreads();   // S + ring row visible

    // diagonal 3-point stencil (bf16 reads) + cost + 2-chain med3 top-8
    const u16* r0 = &Rh[sx * 70 + jxs];
    const u16* r1 = r0 + 71;    // (sx+1)*70 + jxs + 1
    const u16* r2 = r0 + 142;   // (sx+2)*70 + jxs + 2
    const float* kkr = &kkbuf[(jt << 6) + jxs];
    int jbase = (jy << 6) + jxs;
#pragma unroll
    for (int jj = 0; jj < 16; ++jj) {
      float s3 = bf2f(r0[jj]) + bf2f(r1[jj]) + bf2f(r2[jj]);
      float cost = kkr[jj] - 2.f * s3;
      u32 key = (ordenc(cost) & 0xFFFFF000u) | (u32)(jbase + jj);
      if (jj & 1) kins(k8b, key); else kins(k8a, key);
    }
  }

#pragma unroll
  for (int s = 0; s < KTOP; ++s) kins(k8a, k8b[s]);

  // block merge: 4 segments per query -> per-16th top-8
  __syncthreads();
  u32* lbuf = (u32*)ring;   // 128 queries x 32 keys = 16 KB
  int qloc = (h << 6) + sx;
#pragma unroll
  for (int s = 0; s < KTOP; ++s) lbuf[(qloc << 5) + (sseg << 3) + s] = k8a[s];
  __syncthreads();
  if (t < 128) {
    u32 m8a[KTOP], m8b[KTOP];
#pragma unroll
    for (int s = 0; s < KTOP; ++s) { m8a[s] = 0xFFFFFFFFu; m8b[s] = 0xFFFFFFFFu; }
    const u32* lp = &lbuf[t << 5];
#pragma unroll
    for (int e = 0; e < 16; ++e) {
      kins(m8a, lp[e * 2]);
      kins(m8b, lp[e * 2 + 1]);
    }
#pragma unroll
    for (int s = 0; s < KTOP; ++s) kins(m8a, m8b[s]);
    int qi = ((iy0 + (t >> 6)) << 6) + (t & 63);
    u32* dst = cand + (((size_t)(b << 12) + qi) << 7) + (e16 << 3);
#pragma unroll
    for (int s = 0; s < KTOP; ++s) dst[s] = m8a[s];
  }
}

// ---------------- kernel 4 (fused): 2x64 bitonic sort + merge + exact fp32 rescore ----
__launch_bounds__(1024)
__global__ void fused_out_kernel(const float* __restrict__ qsrc, const float* __restrict__ ksrc,
                                 const float* __restrict__ kkg, const u32* __restrict__ cand,
                                 const float* __restrict__ v, const float* __restrict__ vt,
                                 float* __restrict__ out, int use_vt) {
  __shared__ float otile[64 * 17];
  int t = threadIdx.x;
  int wid = t >> 6, lane = t & 63;
  int qi = blockIdx.x * 16 + wid;          // == (b<<12) + qpix
  int b = qi >> 12, qpix = qi & 4095;

  // ---- phase A: two 64-lane bitonic sorts + 8-wide half-cleaner merge ----
  u32 c0 = cand[((size_t)qi << 7) + lane];
  u32 c1 = cand[((size_t)qi << 7) + 64 + lane];
#pragma unroll
  for (int kk2 = 2; kk2 <= 64; kk2 <<= 1) {
#pragma unroll
    for (int j2 = kk2 >> 1; j2 > 0; j2 >>= 1) {
      bool up = ((lane & kk2) == 0);
      bool lowr = ((lane & j2) == 0);
      u32 o0 = (u32)__shfl_xor((int)c0, j2);
      u32 mn0 = c0 < o0 ? c0 : o0;
      u32 mx0 = c0 < o0 ? o0 : c0;
      c0 = (up == lowr) ? mn0 : mx0;
      u32 o1 = (u32)__shfl_xor((int)c1, j2);
      u32 mn1 = c1 < o1 ? c1 : o1;
      u32 mx1 = c1 < o1 ? o1 : c1;
      c1 = (up == lowr) ? mn1 : mx1;
    }
  }
  // lanes 0..7: L[i] = min(A[i], B[7-i]) is bitonic & contains the 8 smallest
  u32 brev = (u32)__shfl((int)c1, 7 - (lane & 7));
  u32 mn = c0 < brev ? c0 : brev;
#pragma unroll
  for (int j2 = 4; j2 >= 1; j2 >>= 1) {
    u32 o = (u32)__shfl_xor((int)mn, j2);
    u32 lo2 = mn < o ? mn : o;
    u32 hi2 = mn < o ? o : mn;
    mn = ((lane & j2) == 0) ? lo2 : hi2;
  }
  u32 key = mn;   // lanes 0-7 hold global top-8 ascending

  // ---- phase B: EXACT fp32 rescore from original q,k; slot s=lane>>3, g=lane&7 ----
  int s = lane >> 3, g = lane & 7;
  int j = (u32)__shfl((int)key, s) & 0xFFFu;
  int yi = qpix >> 6, xi = qpix & 63;
  int yj = j >> 6, xj = j & 63;
  const float* qb = qsrc + ((size_t)b << 18);
  const float* kb = ksrc + ((size_t)b << 18);

  float dot = 0.f;
#pragma unroll
  for (int di = 0; di < 3; ++di) {
    int qy = yi + di - 1, ky = yj + di - 1;
    bool vy = ((unsigned)qy < 64u) && ((unsigned)ky < 64u);
#pragma unroll
    for (int dj = 0; dj < 3; ++dj) {
      int qx = xi + dj - 1, kx = xj + dj - 1;
      bool ok = vy && ((unsigned)qx < 64u) && ((unsigned)kx < 64u);
      const float* qp = qb + ((qy & 63) << 6) + (qx & 63) + ((size_t)(g << 3) << 12);
      const float* kp = kb + ((ky & 63) << 6) + (kx & 63) + ((size_t)(g << 3) << 12);
      float pacc = 0.f;
#pragma unroll
      for (int e = 0; e < 8; ++e)
        pacc = fmaf(qp[(size_t)e << 12], kp[(size_t)e << 12], pacc);
      dot += ok ? pacc : 0.f;
    }
  }
#pragma unroll
  for (int off = 1; off < 8; off <<= 1) dot += __shfl_xor(dot, off);
  float cost = kkg[(b << 12) + j] - 2.f * dot;

  // ---- phase C: softmax over the 8 slots ----
  float m = cost;
#pragma unroll
  for (int off = 8; off < 64; off <<= 1) m = fminf(m, __shfl_xor(m, off));
  float w = __expf(m - cost);
  float wsum = w;
#pragma unroll
  for (int off = 8; off < 64; off <<= 1) wsum += __shfl_xor(wsum, off);
  w /= wsum;

  // ---- phase D: gather v, channel per lane ----
  float wk2[8]; int jk[8];
#pragma unroll
  for (int ss = 0; ss < 8; ++ss) {
    wk2[ss] = __shfl(w, ss << 3);
    jk[ss]  = __shfl(j, ss << 3);
  }
  float acc = 0.f;
  if (use_vt) {
    const float* vtb = vt + ((size_t)b << 18);
#pragma unroll
    for (int ss = 0; ss < 8; ++ss) acc += wk2[ss] * vtb[(jk[ss] << 6) + lane];
  } else {
    const float* vb = v + ((size_t)b << 18);
#pragma unroll
    for (int ss = 0; ss < 8; ++ss) acc += wk2[ss] * vb[(lane << 12) + jk[ss]];
  }
  otile[lane * 17 + wid] = acc;
  __syncthreads();

  int c2 = t >> 4, qq = t & 15;
  int pixbase = (blockIdx.x & 255) << 4;
  out[((size_t)b << 18) + (c2 << 12) + pixbase + qq] = otile[c2 * 17 + qq];
}

extern "C" void kernel_launch(void* const* d_in, const int* in_sizes, int n_in,
                              void* d_out, int out_size, void* d_ws, size_t ws_size,
                              hipStream_t stream) {
  const float* q = (const float*)d_in[0];
  const float* k = (const float*)d_in[1];
  const float* v = (const float*)d_in[2];
  float* out = (float*)d_out;

  char* ws = (char*)d_ws;
  u16*   qh   = (u16*)(ws);
  u16*   kh   = (u16*)(ws + (1u << 20));
  float* nk   = (float*)(ws + (2u << 20));
  float* kkp  = (float*)(ws + (2u << 20) + 32768);
  u32*   cand = (u32*)(ws + (2u << 20) + 65536);
  float* vt   = (float*)(ws + (6u << 20) + 65536);
  size_t need = (8u << 20) + 65536;
  int use_vt = (ws_size >= need) ? 1 : 0;

  prep_kernel<<<use_vt ? 384 : 256, 256, 0, stream>>>(q, k, v, qh, kh, vt, nk);
  kk_kernel<<<32, 256, 0, stream>>>(nk, kkp);
  cost_topk_kernel<<<1024, 512, 0, stream>>>(qh, kh, kkp, cand);
  fused_out_kernel<<<512, 1024, 0, stream>>>(q, k, kkp, cand, v, vt, out, use_vt);
}

// Round 15
// 147.034 us; speedup vs baseline: 1.3903x; 1.3903x over previous
//
#include <hip/hip_runtime.h>

#define KTOP 8
typedef unsigned short u16;
typedef unsigned int u32;
typedef short bf16x8 __attribute__((ext_vector_type(8)));   // 8 bf16 = 4 VGPR
typedef float f32x16 __attribute__((ext_vector_type(16)));  // 32x32 acc

// ---------- ws byte layout (R12's map; 1M-2M and 3M-4M now unused) ----------
// qh @0      : u16[2*64*4096]  1 MB   bf16-hi, [b][y][x*64 + (ch^((x&7)<<3))]
// kh @2M     : u16[...]        1 MB
// nk @4M (f32 8192), kk @4M+32K (f32 8192)
// cand @4M+64K : u32[2*4096*64]  2 MB   (8 subsets x 8 keys)
// vT   @6M+64K : f32[2*4096*64]  2 MB   v transposed (optional)

__device__ __forceinline__ u16 f2bf(float x) {
  u32 u = __builtin_bit_cast(u32, x);
  u32 r = u + 0x7fffu + ((u >> 16) & 1u);
  return (u16)(r >> 16);
}
__device__ __forceinline__ u32 ordenc(float c) {
  u32 u = __builtin_bit_cast(u32, c);
  u32 s = (u32)((int)u >> 31);
  return u ^ (s | 0x80000000u);   // monotone float->uint
}
__device__ __forceinline__ u32 med3u(u32 a, u32 b, u32 c) {
  u32 d;
  asm("v_med3_u32 %0, %1, %2, %3" : "=v"(d) : "v"(a), "v"(b), "v"(c));
  return d;
}
// sorted-ascending top-8 insert: new[0]=min(a0,x), new[p]=med3(a[p-1],a[p],x).
// 8 VALU per candidate, dependency depth 1.
__device__ __forceinline__ void kins(u32 (&k8)[KTOP], u32 x) {
  u32 n0 = k8[0] < x ? k8[0] : x;
#pragma unroll
  for (int p = KTOP - 1; p >= 1; --p) k8[p] = med3u(k8[p - 1], k8[p], x);
  k8[0] = n0;
}

// ---------------- kernel 1: transpose + bf16-hi (+ nk) + vT ----------------
__global__ void prep_kernel(const float* __restrict__ q, const float* __restrict__ k,
                            const float* __restrict__ v,
                            u16* __restrict__ qh, u16* __restrict__ kh,
                            float* __restrict__ vt, float* __restrict__ nk) {
  __shared__ float tile[64][65];
  int bid = blockIdx.x;
  int t = threadIdx.x;

  if (bid >= 256) {                       // ---- v transpose path ----
    int r = bid - 256;
    int b = r >> 6, y = r & 63;
    const float* src = v + (size_t)b * (64 * 4096) + (y << 6);
#pragma unroll
    for (int e = 0; e < 16; ++e) {
      int idx = e * 256 + t;
      int c = idx >> 6, x = idx & 63;
      tile[c][x] = src[(c << 12) + x];
    }
    __syncthreads();
    int x = t >> 2, cg = t & 3;
    float* dst = vt + ((size_t)b << 18) + (((y << 6) + x) << 6) + (cg << 4);
#pragma unroll
    for (int i4 = 0; i4 < 4; ++i4) {
      float4 w;
      w.x = tile[cg * 16 + i4 * 4 + 0][x];
      w.y = tile[cg * 16 + i4 * 4 + 1][x];
      w.z = tile[cg * 16 + i4 * 4 + 2][x];
      w.w = tile[cg * 16 + i4 * 4 + 3][x];
      *(float4*)&dst[i4 * 4] = w;
    }
    return;
  }

  int which = bid >> 7;
  int b = (bid >> 6) & 1;
  int y = bid & 63;
  const float* src = (which ? k : q) + (size_t)b * (64 * 4096) + (y << 6);
#pragma unroll
  for (int e = 0; e < 16; ++e) {
    int idx = e * 256 + t;
    int c = idx >> 6, x = idx & 63;
    tile[c][x] = src[(c << 12) + x];
  }
  __syncthreads();

  int x = t >> 2, cg = t & 3;
  u16 hi[16];
#pragma unroll
  for (int i = 0; i < 16; ++i) hi[i] = f2bf(tile[cg * 16 + i][x]);
  u16* dh = (which ? kh : qh) + ((size_t)(b * 64 + y) << 12);
  int sw = (x & 7) << 3;
#pragma unroll
  for (int cc = 0; cc < 2; ++cc) {
    int base = (x << 6) + ((cg * 16 + cc * 8) ^ sw);
    uint4 wh;
    wh.x = (u32)hi[cc*8+0] | ((u32)hi[cc*8+1] << 16);
    wh.y = (u32)hi[cc*8+2] | ((u32)hi[cc*8+3] << 16);
    wh.z = (u32)hi[cc*8+4] | ((u32)hi[cc*8+5] << 16);
    wh.w = (u32)hi[cc*8+6] | ((u32)hi[cc*8+7] << 16);
    *(uint4*)&dh[base] = wh;
  }
  if (which && t < 64) {
    float s = 0.f;
#pragma unroll
    for (int c = 0; c < 64; ++c) { float vv = tile[c][t]; s += vv * vv; }
    nk[(b << 12) + (y << 6) + t] = s;
  }
}

// ---------------- kernel 2: 3x3 zero-padded stencil -> kk ----------------
__global__ void kk_kernel(const float* __restrict__ nk, float* __restrict__ kk) {
  int p = blockIdx.x * blockDim.x + threadIdx.x;
  int b = p >> 12, pix = p & 4095;
  int y = pix >> 6, x = pix & 63;
  float s = 0.f;
#pragma unroll
  for (int di = -1; di <= 1; ++di)
#pragma unroll
    for (int dj = -1; dj <= 1; ++dj) {
      int yy = y + di, xx = x + dj;
      if ((unsigned)yy < 64u && (unsigned)xx < 64u)
        s += nk[(b << 12) + (yy << 6) + xx];
    }
  kk[p] = s;
}

// ---------------- kernel 3: ring + hi-only MFMA cost + med3 top-8 (R12, verbatim) ----
// grid 512 = b(2) x rowpair(32) x eighth(8); block 512; 2 blocks/CU.
__launch_bounds__(512, 4)
__global__ void cost_topk_kernel(const u16* __restrict__ qh,
                                 const u16* __restrict__ kh,
                                 const float* __restrict__ kkg,
                                 u32* __restrict__ cand) {
  __shared__ __align__(16) u16 ring[4][4096];        // 32 KB, slot = row & 3
  __shared__ float RbBuf[2 * 66 * 67 + 4];           // 2 bordered S tiles
  __shared__ float kkbuf[512];                       // kk rows q0..q0+7

  int bid = blockIdx.x;
  int b   = bid >> 8;
  int rp  = (bid >> 3) & 31;
  int e8  = bid & 7;
  int q0  = e8 << 3;
  int iy0 = rp << 1;

  int t = threadIdx.x;
  int lane = t & 63;
  int wv = t >> 6;
  int h  = wv >> 2;
  int quad = wv & 3;
  int wr = quad >> 1, wc = quad & 1;
  int l31 = lane & 31, lk8 = (lane >> 5) << 3;
  int apix = (wr << 5) + l31;
  int bpix = (wc << 5) + l31;
  int sx = t & 63, sseg = (t >> 6) & 3, jxs = sseg << 4;
  int iy = iy0 + h;

  const u16* qhb = qh + ((size_t)b << 18);
  const u16* khb = kh + ((size_t)b << 18);

  const bf16x8 z8 = {0,0,0,0,0,0,0,0};
  const uint4 z4 = {0u,0u,0u,0u};

  // A fragments (hi only), rows iy-1..iy+1, direct global->VGPR
  bf16x8 qa[3][4];
  int swA = (apix & 7) << 3;
#pragma unroll
  for (int d = 0; d < 3; ++d) {
    int qy = iy - 1 + d;
    bool ok = (unsigned)qy < 64u;
    int rb = (qy & 63) << 12;
#pragma unroll
    for (int c4 = 0; c4 < 4; ++c4) {
      bf16x8 vv = *(const bf16x8*)&qhb[rb + (apix << 6) + (((c4 << 4) + lk8) ^ swA)];
      qa[d][c4] = ok ? vv : z8;
    }
  }

  // zero Rb (borders stay zero); stage kk rows; prefill ring rows q0-1..q0+1
  for (int i = t; i < 2 * 66 * 67 + 4; i += 512) RbBuf[i] = 0.f;
  kkbuf[t] = kkg[(b << 12) + (q0 << 6) + t];
#pragma unroll
  for (int d = 0; d < 3; ++d) {
    int r = q0 - 1 + d;
    bool ok = (unsigned)r < 64u;
    uint4 vv = ok ? *(const uint4*)&khb[((r & 63) << 12) + (t << 3)] : z4;
    *(uint4*)&ring[(r + 4) & 3][t << 3] = vv;
  }
  __syncthreads();

  u32 k8a[KTOP], k8b[KTOP];
#pragma unroll
  for (int s = 0; s < KTOP; ++s) { k8a[s] = 0xFFFFFFFFu; k8b[s] = 0xFFFFFFFFu; }

  int swB = (bpix & 7) << 3;
  float* Rh = &RbBuf[h * (66 * 67)];

  for (int jt = 0; jt < 8; ++jt) {
    int jy = q0 + jt;
    // prefetch next ring row (global->reg; LDS write after barrier)
    int pr = jy + 2;
    bool pok = (jt < 7) && (pr < 64);
    uint4 pf = pok ? *(const uint4*)&khb[((pr & 63) << 12) + (t << 3)] : z4;

    // ---- MFMA: two independent acc chains (halve dependent-MFMA latency) ----
    f32x16 acc0, acc1;
#pragma unroll
    for (int i = 0; i < 16; ++i) { acc0[i] = 0.f; acc1[i] = 0.f; }
    __builtin_amdgcn_s_setprio(1);
#pragma unroll
    for (int d = 0; d < 3; ++d) {
      const u16* rg = ring[(jy - 1 + d) & 3];
#pragma unroll
      for (int c4 = 0; c4 < 4; ++c4) {
        bf16x8 bh = *(const bf16x8*)&rg[(bpix << 6) + (((c4 << 4) + lk8) ^ swB)];
        if ((d ^ c4) & 1)
          acc1 = __builtin_amdgcn_mfma_f32_32x32x16_bf16(qa[d][c4], bh, acc1, 0, 0, 0);
        else
          acc0 = __builtin_amdgcn_mfma_f32_32x32x16_bf16(qa[d][c4], bh, acc0, 0, 0, 0);
      }
    }
    __builtin_amdgcn_s_setprio(0);
    __syncthreads();   // prev stencil reads of Rb done (ring write slot disjoint)

    // C-write (col=lane&31, row=(r&3)+8*(r>>2)+4*(lane>>5)) into bordered tile
#pragma unroll
    for (int r = 0; r < 16; ++r) {
      int row = (wr << 5) + (r & 3) + ((r >> 2) << 3) + ((lane >> 5) << 2);
      Rh[(row + 1) * 67 + (wc << 5) + l31 + 1] = acc0[r] + acc1[r];
    }
    if (jt < 7) *(uint4*)&ring[pr & 3][t << 3] = pf;
    __syncthreads();   // S + ring row visible

    // diagonal 3-point stencil + cost + 2-chain med3 top-8
    float a16[16];
    {
      const float* rm = &Rh[sx * 67 + jxs];
      const float* rc = &Rh[(sx + 1) * 67 + jxs];
      const float* rq = &Rh[(sx + 2) * 67 + jxs];
#pragma unroll
      for (int jj = 0; jj < 16; ++jj)
        a16[jj] = rm[jj] + rc[jj + 1] + rq[jj + 2];
    }
    const float* kkr = &kkbuf[(jt << 6) + jxs];
    int jbase = (jy << 6) + jxs;
#pragma unroll
    for (int jj = 0; jj < 16; ++jj) {
      float cost = kkr[jj] - 2.f * a16[jj];
      u32 key = (ordenc(cost) & 0xFFFFF000u) | (u32)(jbase + jj);
      if (jj & 1) kins(k8b, key); else kins(k8a, key);
    }
  }

#pragma unroll
  for (int s = 0; s < KTOP; ++s) kins(k8a, k8b[s]);

  // block merge: 4 segments per query -> per-eighth top-8
  __syncthreads();
  u32* lbuf = (u32*)ring;   // 128 queries x 32 keys = 16 KB
  int qloc = (h << 6) + sx;
#pragma unroll
  for (int s = 0; s < KTOP; ++s) lbuf[(qloc << 5) + (sseg << 3) + s] = k8a[s];
  __syncthreads();
  if (t < 128) {
    u32 m8a[KTOP], m8b[KTOP];
#pragma unroll
    for (int s = 0; s < KTOP; ++s) { m8a[s] = 0xFFFFFFFFu; m8b[s] = 0xFFFFFFFFu; }
    const u32* lp = &lbuf[t << 5];
#pragma unroll
    for (int e = 0; e < 16; ++e) {
      kins(m8a, lp[e * 2]);
      kins(m8b, lp[e * 2 + 1]);
    }
#pragma unroll
    for (int s = 0; s < KTOP; ++s) kins(m8a, m8b[s]);
    int qi = ((iy0 + (t >> 6)) << 6) + (t & 63);
    u32* dst = cand + (((size_t)(b << 12) + qi) << 6) + (e8 << 3);
#pragma unroll
    for (int s = 0; s < KTOP; ++s) dst[s] = m8a[s];
  }
}

// ---------------- kernel 4 (fused): 64-key bitonic sort + EXACT fp32 rescore ----------
__launch_bounds__(1024)
__global__ void fused_out_kernel(const float* __restrict__ qsrc, const float* __restrict__ ksrc,
                                 const float* __restrict__ kkg, const u32* __restrict__ cand,
                                 const float* __restrict__ v, const float* __restrict__ vt,
                                 float* __restrict__ out, int use_vt) {
  __shared__ float otile[64 * 17];
  int t = threadIdx.x;
  int wid = t >> 6, lane = t & 63;
  int qi = blockIdx.x * 16 + wid;          // == (b<<12) + qpix
  int b = qi >> 12, qpix = qi & 4095;

  // ---- phase A: 64-lane bitonic sort of this query's 64 candidate keys (R12) ----
  u32 key = cand[((size_t)qi << 6) + lane];
#pragma unroll
  for (int kk2 = 2; kk2 <= 64; kk2 <<= 1) {
#pragma unroll
    for (int j2 = kk2 >> 1; j2 > 0; j2 >>= 1) {
      u32 o = (u32)__shfl_xor((int)key, j2);
      bool up = ((lane & kk2) == 0);
      bool lowr = ((lane & j2) == 0);
      u32 mn = key < o ? key : o;
      u32 mx = key < o ? o : key;
      key = (up == lowr) ? mn : mx;
    }
  }

  // ---- phase B: EXACT fp32 rescore from original q,k (validated R13) ----
  int s = lane >> 3, g = lane & 7;
  int j = (u32)__shfl((int)key, s) & 0xFFFu;
  int yi = qpix >> 6, xi = qpix & 63;
  int yj = j >> 6, xj = j & 63;
  const float* qb = qsrc + ((size_t)b << 18);
  const float* kb = ksrc + ((size_t)b << 18);

  float dot = 0.f;
#pragma unroll
  for (int di = 0; di < 3; ++di) {
    int qy = yi + di - 1, ky = yj + di - 1;
    bool vy = ((unsigned)qy < 64u) && ((unsigned)ky < 64u);
#pragma unroll
    for (int dj = 0; dj < 3; ++dj) {
      int qx = xi + dj - 1, kx = xj + dj - 1;
      bool ok = vy && ((unsigned)qx < 64u) && ((unsigned)kx < 64u);
      const float* qp = qb + ((qy & 63) << 6) + (qx & 63) + ((size_t)(g << 3) << 12);
      const float* kp = kb + ((ky & 63) << 6) + (kx & 63) + ((size_t)(g << 3) << 12);
      float pacc = 0.f;
#pragma unroll
      for (int e = 0; e < 8; ++e)
        pacc = fmaf(qp[(size_t)e << 12], kp[(size_t)e << 12], pacc);
      dot += ok ? pacc : 0.f;
    }
  }
#pragma unroll
  for (int off = 1; off < 8; off <<= 1) dot += __shfl_xor(dot, off);
  float cost = kkg[(b << 12) + j] - 2.f * dot;

  // ---- phase C: softmax over the 8 slots ----
  float m = cost;
#pragma unroll
  for (int off = 8; off < 64; off <<= 1) m = fminf(m, __shfl_xor(m, off));
  float w = __expf(m - cost);
  float wsum = w;
#pragma unroll
  for (int off = 8; off < 64; off <<= 1) wsum += __shfl_xor(wsum, off);
  w /= wsum;

  // ---- phase D: gather v, channel per lane ----
  float wk2[8]; int jk[8];
#pragma unroll
  for (int ss = 0; ss < 8; ++ss) {
    wk2[ss] = __shfl(w, ss << 3);
    jk[ss]  = __shfl(j, ss << 3);
  }
  float acc = 0.f;
  if (use_vt) {
    const float* vtb = vt + ((size_t)b << 18);
#pragma unroll
    for (int ss = 0; ss < 8; ++ss) acc += wk2[ss] * vtb[(jk[ss] << 6) + lane];
  } else {
    const float* vb = v + ((size_t)b << 18);
#pragma unroll
    for (int ss = 0; ss < 8; ++ss) acc += wk2[ss] * vb[(lane << 12) + jk[ss]];
  }
  otile[lane * 17 + wid] = acc;
  __syncthreads();

  int c2 = t >> 4, qq = t & 15;
  int pixbase = (blockIdx.x & 255) << 4;
  out[((size_t)b << 18) + (c2 << 12) + pixbase + qq] = otile[c2 * 17 + qq];
}

extern "C" void kernel_launch(void* const* d_in, const int* in_sizes, int n_in,
                              void* d_out, int out_size, void* d_ws, size_t ws_size,
                              hipStream_t stream) {
  const float* q = (const float*)d_in[0];
  const float* k = (const float*)d_in[1];
  const float* v = (const float*)d_in[2];
  float* out = (float*)d_out;

  char* ws = (char*)d_ws;
  u16*   qh   = (u16*)(ws);
  u16*   kh   = (u16*)(ws + (2u << 20));
  float* nk   = (float*)(ws + (4u << 20));
  float* kkp  = (float*)(ws + (4u << 20) + 32768);
  u32*   cand = (u32*)(ws + (4u << 20) + 65536);
  float* vt   = (float*)(ws + (6u << 20) + 65536);
  size_t need = (8u << 20) + 65536;
  int use_vt = (ws_size >= need) ? 1 : 0;

  prep_kernel<<<use_vt ? 384 : 256, 256, 0, stream>>>(q, k, v, qh, kh, vt, nk);
  kk_kernel<<<32, 256, 0, stream>>>(nk, kkp);
  cost_topk_kernel<<<512, 512, 0, stream>>>(qh, kh, kkp, cand);
  fused_out_kernel<<<512, 1024, 0, stream>>>(q, k, kkp, cand, v, vt, out, use_vt);
}

// Round 16
// 57.308 us; speedup vs baseline: 3.5670x; 2.5657x over previous
//
#include <hip/hip_runtime.h>

#define KTOP 8
typedef unsigned short u16;
typedef unsigned int u32;
typedef short bf16x8 __attribute__((ext_vector_type(8)));   // 8 bf16 = 4 VGPR
typedef float f32x16 __attribute__((ext_vector_type(16)));  // 32x32 acc

// ---------- ws byte layout ----------
// qh @0, ql @1M, kh @2M, kl @3M : u16[2*64*4096] each, [b][y][x*64 + (ch^((x&7)<<3))]
// nk @4M (f32 8192), kk @4M+32K (f32 8192)
// cand @4M+64K : u32[2*4096*64]  (2 MB)  quantized keys
// vT   @6M+64K : f32[2*4096*64]  (2 MB)  v transposed [b][pix][ch]  (optional)

__device__ __forceinline__ u16 f2bf(float x) {
  u32 u = __builtin_bit_cast(u32, x);
  u32 r = u + 0x7fffu + ((u >> 16) & 1u);
  return (u16)(r >> 16);
}
__device__ __forceinline__ float bf2f(u16 h) {
  u32 u = ((u32)h) << 16;
  return __builtin_bit_cast(float, u);
}
__device__ __forceinline__ u32 ordenc(float c) {
  u32 u = __builtin_bit_cast(u32, c);
  u32 s = (u32)((int)u >> 31);
  return u ^ (s | 0x80000000u);   // monotone float->uint
}
__device__ __forceinline__ u32 med3u(u32 a, u32 b, u32 c) {
  u32 d;
  asm("v_med3_u32 %0, %1, %2, %3" : "=v"(d) : "v"(a), "v"(b), "v"(c));
  return d;
}
// sorted-ascending top-8 insert: new[0]=min(a0,x), new[p]=med3(a[p-1],a[p],x).
// 8 VALU per candidate, dependency depth 1.
__device__ __forceinline__ void kins(u32 (&k8)[KTOP], u32 x) {
  u32 n0 = k8[0] < x ? k8[0] : x;
#pragma unroll
  for (int p = KTOP - 1; p >= 1; --p) k8[p] = med3u(k8[p - 1], k8[p], x);
  k8[0] = n0;
}

// ---------------- kernel 1: transpose + bf16 hi/lo split (+ nk) + vT ----------------
__global__ void prep_kernel(const float* __restrict__ q, const float* __restrict__ k,
                            const float* __restrict__ v,
                            u16* __restrict__ qh, u16* __restrict__ ql,
                            u16* __restrict__ kh, u16* __restrict__ kl,
                            float* __restrict__ vt, float* __restrict__ nk) {
  __shared__ float tile[64][65];
  int bid = blockIdx.x;
  int t = threadIdx.x;

  if (bid >= 256) {                       // ---- v transpose path ----
    int r = bid - 256;
    int b = r >> 6, y = r & 63;
    const float* src = v + (size_t)b * (64 * 4096) + (y << 6);
#pragma unroll
    for (int e = 0; e < 16; ++e) {
      int idx = e * 256 + t;
      int c = idx >> 6, x = idx & 63;
      tile[c][x] = src[(c << 12) + x];
    }
    __syncthreads();
    int x = t >> 2, cg = t & 3;
    float* dst = vt + ((size_t)b << 18) + (((y << 6) + x) << 6) + (cg << 4);
#pragma unroll
    for (int i4 = 0; i4 < 4; ++i4) {
      float4 w;
      w.x = tile[cg * 16 + i4 * 4 + 0][x];
      w.y = tile[cg * 16 + i4 * 4 + 1][x];
      w.z = tile[cg * 16 + i4 * 4 + 2][x];
      w.w = tile[cg * 16 + i4 * 4 + 3][x];
      *(float4*)&dst[i4 * 4] = w;
    }
    return;
  }

  int which = bid >> 7;
  int b = (bid >> 6) & 1;
  int y = bid & 63;
  const float* src = (which ? k : q) + (size_t)b * (64 * 4096) + (y << 6);
#pragma unroll
  for (int e = 0; e < 16; ++e) {
    int idx = e * 256 + t;
    int c = idx >> 6, x = idx & 63;
    tile[c][x] = src[(c << 12) + x];
  }
  __syncthreads();

  int x = t >> 2, cg = t & 3;
  u16 hi[16], lo[16];
#pragma unroll
  for (int i = 0; i < 16; ++i) {
    float val = tile[cg * 16 + i][x];
    u16 h = f2bf(val);
    hi[i] = h;
    lo[i] = f2bf(val - bf2f(h));
  }
  u16* dh = (which ? kh : qh) + ((size_t)(b * 64 + y) << 12);
  u16* dl = (which ? kl : ql) + ((size_t)(b * 64 + y) << 12);
  int sw = (x & 7) << 3;
#pragma unroll
  for (int cc = 0; cc < 2; ++cc) {
    int base = (x << 6) + ((cg * 16 + cc * 8) ^ sw);
    uint4 wh, wl;
    wh.x = (u32)hi[cc*8+0] | ((u32)hi[cc*8+1] << 16);
    wh.y = (u32)hi[cc*8+2] | ((u32)hi[cc*8+3] << 16);
    wh.z = (u32)hi[cc*8+4] | ((u32)hi[cc*8+5] << 16);
    wh.w = (u32)hi[cc*8+6] | ((u32)hi[cc*8+7] << 16);
    wl.x = (u32)lo[cc*8+0] | ((u32)lo[cc*8+1] << 16);
    wl.y = (u32)lo[cc*8+2] | ((u32)lo[cc*8+3] << 16);
    wl.z = (u32)lo[cc*8+4] | ((u32)lo[cc*8+5] << 16);
    wl.w = (u32)lo[cc*8+6] | ((u32)lo[cc*8+7] << 16);
    *(uint4*)&dh[base] = wh;
    *(uint4*)&dl[base] = wl;
  }
  if (which && t < 64) {
    float s = 0.f;
#pragma unroll
    for (int c = 0; c < 64; ++c) { float vv = tile[c][t]; s += vv * vv; }
    nk[(b << 12) + (y << 6) + t] = s;
  }
}

// ---------------- kernel 2: 3x3 zero-padded stencil -> kk ----------------
__global__ void kk_kernel(const float* __restrict__ nk, float* __restrict__ kk) {
  int p = blockIdx.x * blockDim.x + threadIdx.x;
  int b = p >> 12, pix = p & 4095;
  int y = pix >> 6, x = pix & 63;
  float s = 0.f;
#pragma unroll
  for (int di = -1; di <= 1; ++di)
#pragma unroll
    for (int dj = -1; dj <= 1; ++dj) {
      int yy = y + di, xx = x + dj;
      if ((unsigned)yy < 64u && (unsigned)xx < 64u)
        s += nk[(b << 12) + (yy << 6) + xx];
    }
  kk[p] = s;
}

// ---------------- kernel 3: ring + hi-only MFMA cost + med3 top-8 ----------------
// grid 512 = b(2) x rowpair(32) x eighth(8); block 512; 2 blocks/CU.
// MFMA split into 2 independent acc chains + s_setprio around MFMA cluster.
__launch_bounds__(512, 4)
__global__ void cost_topk_kernel(const u16* __restrict__ qh,
                                 const u16* __restrict__ kh,
                                 const float* __restrict__ kkg,
                                 u32* __restrict__ cand) {
  __shared__ __align__(16) u16 ring[4][4096];        // 32 KB, slot = row & 3
  __shared__ float RbBuf[2 * 66 * 67 + 4];           // 2 bordered S tiles
  __shared__ float kkbuf[512];                       // kk rows q0..q0+7

  int bid = blockIdx.x;
  int b   = bid >> 8;
  int rp  = (bid >> 3) & 31;
  int e8  = bid & 7;
  int q0  = e8 << 3;
  int iy0 = rp << 1;

  int t = threadIdx.x;
  int lane = t & 63;
  int wv = t >> 6;
  int h  = wv >> 2;
  int quad = wv & 3;
  int wr = quad >> 1, wc = quad & 1;
  int l31 = lane & 31, lk8 = (lane >> 5) << 3;
  int apix = (wr << 5) + l31;
  int bpix = (wc << 5) + l31;
  int sx = t & 63, sseg = (t >> 6) & 3, jxs = sseg << 4;
  int iy = iy0 + h;

  const u16* qhb = qh + ((size_t)b << 18);
  const u16* khb = kh + ((size_t)b << 18);

  const bf16x8 z8 = {0,0,0,0,0,0,0,0};
  const uint4 z4 = {0u,0u,0u,0u};

  // A fragments (hi only), rows iy-1..iy+1, direct global->VGPR
  bf16x8 qa[3][4];
  int swA = (apix & 7) << 3;
#pragma unroll
  for (int d = 0; d < 3; ++d) {
    int qy = iy - 1 + d;
    bool ok = (unsigned)qy < 64u;
    int rb = (qy & 63) << 12;
#pragma unroll
    for (int c4 = 0; c4 < 4; ++c4) {
      bf16x8 vv = *(const bf16x8*)&qhb[rb + (apix << 6) + (((c4 << 4) + lk8) ^ swA)];
      qa[d][c4] = ok ? vv : z8;
    }
  }

  // zero Rb (borders stay zero); stage kk rows; prefill ring rows q0-1..q0+1
  for (int i = t; i < 2 * 66 * 67 + 4; i += 512) RbBuf[i] = 0.f;
  kkbuf[t] = kkg[(b << 12) + (q0 << 6) + t];
#pragma unroll
  for (int d = 0; d < 3; ++d) {
    int r = q0 - 1 + d;
    bool ok = (unsigned)r < 64u;
    uint4 vv = ok ? *(const uint4*)&khb[((r & 63) << 12) + (t << 3)] : z4;
    *(uint4*)&ring[(r + 4) & 3][t << 3] = vv;
  }
  __syncthreads();

  u32 k8a[KTOP], k8b[KTOP];
#pragma unroll
  for (int s = 0; s < KTOP; ++s) { k8a[s] = 0xFFFFFFFFu; k8b[s] = 0xFFFFFFFFu; }

  int swB = (bpix & 7) << 3;
  float* Rh = &RbBuf[h * (66 * 67)];

  for (int jt = 0; jt < 8; ++jt) {
    int jy = q0 + jt;
    // prefetch next ring row (global->reg; LDS write after barrier)
    int pr = jy + 2;
    bool pok = (jt < 7) && (pr < 64);
    uint4 pf = pok ? *(const uint4*)&khb[((pr & 63) << 12) + (t << 3)] : z4;

    // ---- MFMA: two independent acc chains (halve dependent-MFMA latency) ----
    f32x16 acc0, acc1;
#pragma unroll
    for (int i = 0; i < 16; ++i) { acc0[i] = 0.f; acc1[i] = 0.f; }
    __builtin_amdgcn_s_setprio(1);
#pragma unroll
    for (int d = 0; d < 3; ++d) {
      const u16* rg = ring[(jy - 1 + d) & 3];
#pragma unroll
      for (int c4 = 0; c4 < 4; ++c4) {
        bf16x8 bh = *(const bf16x8*)&rg[(bpix << 6) + (((c4 << 4) + lk8) ^ swB)];
        if ((d ^ c4) & 1)
          acc1 = __builtin_amdgcn_mfma_f32_32x32x16_bf16(qa[d][c4], bh, acc1, 0, 0, 0);
        else
          acc0 = __builtin_amdgcn_mfma_f32_32x32x16_bf16(qa[d][c4], bh, acc0, 0, 0, 0);
      }
    }
    __builtin_amdgcn_s_setprio(0);
    __syncthreads();   // prev stencil reads of Rb done (ring write slot disjoint)

    // C-write (col=lane&31, row=(r&3)+8*(r>>2)+4*(lane>>5)) into bordered tile
#pragma unroll
    for (int r = 0; r < 16; ++r) {
      int row = (wr << 5) + (r & 3) + ((r >> 2) << 3) + ((lane >> 5) << 2);
      Rh[(row + 1) * 67 + (wc << 5) + l31 + 1] = acc0[r] + acc1[r];
    }
    if (jt < 7) *(uint4*)&ring[pr & 3][t << 3] = pf;
    __syncthreads();   // S + ring row visible

    // diagonal 3-point stencil + cost + 2-chain med3 top-8
    float a16[16];
    {
      const float* rm = &Rh[sx * 67 + jxs];
      const float* rc = &Rh[(sx + 1) * 67 + jxs];
      const float* rq = &Rh[(sx + 2) * 67 + jxs];
#pragma unroll
      for (int jj = 0; jj < 16; ++jj)
        a16[jj] = rm[jj] + rc[jj + 1] + rq[jj + 2];
    }
    const float* kkr = &kkbuf[(jt << 6) + jxs];
    int jbase = (jy << 6) + jxs;
#pragma unroll
    for (int jj = 0; jj < 16; ++jj) {
      float cost = kkr[jj] - 2.f * a16[jj];
      u32 key = (ordenc(cost) & 0xFFFFF000u) | (u32)(jbase + jj);
      if (jj & 1) kins(k8b, key); else kins(k8a, key);
    }
  }

#pragma unroll
  for (int s = 0; s < KTOP; ++s) kins(k8a, k8b[s]);

  // block merge: 4 segments per query -> per-eighth top-8
  __syncthreads();
  u32* lbuf = (u32*)ring;   // 128 queries x 32 keys = 16 KB
  int qloc = (h << 6) + sx;
#pragma unroll
  for (int s = 0; s < KTOP; ++s) lbuf[(qloc << 5) + (sseg << 3) + s] = k8a[s];
  __syncthreads();
  if (t < 128) {
    u32 m8a[KTOP], m8b[KTOP];
#pragma unroll
    for (int s = 0; s < KTOP; ++s) { m8a[s] = 0xFFFFFFFFu; m8b[s] = 0xFFFFFFFFu; }
    const u32* lp = &lbuf[t << 5];
#pragma unroll
    for (int e = 0; e < 16; ++e) {
      kins(m8a, lp[e * 2]);
      kins(m8b, lp[e * 2 + 1]);
    }
#pragma unroll
    for (int s = 0; s < KTOP; ++s) kins(m8a, m8b[s]);
    int qi = ((iy0 + (t >> 6)) << 6) + (t & 63);
    u32* dst = cand + (((size_t)(b << 12) + qi) << 6) + (e8 << 3);
#pragma unroll
    for (int s = 0; s < KTOP; ++s) dst[s] = m8a[s];
  }
}

// ---------------- kernel 4 (fused): bitonic merge + hi/lo rescore + softmax + gather ----
__launch_bounds__(1024)
__global__ void fused_out_kernel(const u16* __restrict__ qh, const u16* __restrict__ ql,
                                 const u16* __restrict__ kh, const u16* __restrict__ kl,
                                 const float* __restrict__ kkg, const u32* __restrict__ cand,
                                 const float* __restrict__ v, const float* __restrict__ vt,
                                 float* __restrict__ out, int use_vt) {
  __shared__ float otile[64 * 17];
  int t = threadIdx.x;
  int wid = t >> 6, lane = t & 63;
  int qi = blockIdx.x * 16 + wid;          // == (b<<12) + qpix
  int b = qi >> 12, qpix = qi & 4095;

  // ---- phase A: 64-lane bitonic sort of this query's 64 candidate keys ----
  u32 key = cand[((size_t)qi << 6) + lane];
#pragma unroll
  for (int kk2 = 2; kk2 <= 64; kk2 <<= 1) {
#pragma unroll
    for (int j2 = kk2 >> 1; j2 > 0; j2 >>= 1) {
      u32 o = (u32)__shfl_xor((int)key, j2);
      bool up = ((lane & kk2) == 0);
      bool lowr = ((lane & j2) == 0);
      u32 mn = key < o ? key : o;
      u32 mx = key < o ? o : key;
      key = (up == lowr) ? mn : mx;
    }
  }

  // ---- phase B: hi/lo rescore; slot s = lane>>3, ch group g = lane&7 ----
  int s = lane >> 3, g = lane & 7;
  int j = (u32)__shfl((int)key, s) & 0xFFFu;
  int yi = qpix >> 6, xi = qpix & 63;
  int yj = j >> 6, xj = j & 63;
  const u16* qhb = qh + ((size_t)b << 18);
  const u16* qlb = ql + ((size_t)b << 18);
  const u16* khb = kh + ((size_t)b << 18);
  const u16* klb = kl + ((size_t)b << 18);

  float dot = 0.f;
#pragma unroll
  for (int di = 0; di < 3; ++di) {
    int qy = yi + di - 1, ky = yj + di - 1;
    bool vy = ((unsigned)qy < 64u) && ((unsigned)ky < 64u);
#pragma unroll
    for (int dj = 0; dj < 3; ++dj) {
      int qx = xi + dj - 1, kx = xj + dj - 1;
      bool ok = vy && ((unsigned)qx < 64u) && ((unsigned)kx < 64u);
      int qxc = qx & 63, kxc = kx & 63;
      int qa = ((qy & 63) << 12) + (qxc << 6) + ((g << 3) ^ ((qxc & 7) << 3));
      int ka = ((ky & 63) << 12) + (kxc << 6) + ((g << 3) ^ ((kxc & 7) << 3));
      uint4 aqh = *(const uint4*)&qhb[qa];
      uint4 aql = *(const uint4*)&qlb[qa];
      uint4 akh = *(const uint4*)&khb[ka];
      uint4 akl = *(const uint4*)&klb[ka];
      const u32* wqh = (const u32*)&aqh;
      const u32* wql = (const u32*)&aql;
      const u32* wkh = (const u32*)&akh;
      const u32* wkl = (const u32*)&akl;
      float pacc = 0.f;
#pragma unroll
      for (int e = 0; e < 4; ++e) {
        float q0 = __builtin_bit_cast(float, wqh[e] << 16) +
                   __builtin_bit_cast(float, wql[e] << 16);
        float q1 = __builtin_bit_cast(float, wqh[e] & 0xFFFF0000u) +
                   __builtin_bit_cast(float, wql[e] & 0xFFFF0000u);
        float k0 = __builtin_bit_cast(float, wkh[e] << 16) +
                   __builtin_bit_cast(float, wkl[e] << 16);
        float k1 = __builtin_bit_cast(float, wkh[e] & 0xFFFF0000u) +
                   __builtin_bit_cast(float, wkl[e] & 0xFFFF0000u);
        pacc = fmaf(q0, k0, pacc);
        pacc = fmaf(q1, k1, pacc);
      }
      dot += ok ? pacc : 0.f;
    }
  }
#pragma unroll
  for (int off = 1; off < 8; off <<= 1) dot += __shfl_xor(dot, off);
  float cost = kkg[(b << 12) + j] - 2.f * dot;

  // ---- phase C: softmax over the 8 slots ----
  float m = cost;
#pragma unroll
  for (int off = 8; off < 64; off <<= 1) m = fminf(m, __shfl_xor(m, off));
  float w = __expf(m - cost);
  float wsum = w;
#pragma unroll
  for (int off = 8; off < 64; off <<= 1) wsum += __shfl_xor(wsum, off);
  w /= wsum;

  // ---- phase D: gather v, channel per lane ----
  float wk2[8]; int jk[8];
#pragma unroll
  for (int ss = 0; ss < 8; ++ss) {
    wk2[ss] = __shfl(w, ss << 3);
    jk[ss]  = __shfl(j, ss << 3);
  }
  float acc = 0.f;
  if (use_vt) {
    const float* vtb = vt + ((size_t)b << 18);
#pragma unroll
    for (int ss = 0; ss < 8; ++ss) acc += wk2[ss] * vtb[(jk[ss] << 6) + lane];
  } else {
    const float* vb = v + ((size_t)b << 18);
#pragma unroll
    for (int ss = 0; ss < 8; ++ss) acc += wk2[ss] * vb[(lane << 12) + jk[ss]];
  }
  otile[lane * 17 + wid] = acc;
  __syncthreads();

  int c2 = t >> 4, qq = t & 15;
  int pixbase = (blockIdx.x & 255) << 4;
  out[((size_t)b << 18) + (c2 << 12) + pixbase + qq] = otile[c2 * 17 + qq];
}

extern "C" void kernel_launch(void* const* d_in, const int* in_sizes, int n_in,
                              void* d_out, int out_size, void* d_ws, size_t ws_size,
                              hipStream_t stream) {
  const float* q = (const float*)d_in[0];
  const float* k = (const float*)d_in[1];
  const float* v = (const float*)d_in[2];
  float* out = (float*)d_out;

  char* ws = (char*)d_ws;
  u16*   qh   = (u16*)(ws);
  u16*   ql   = (u16*)(ws + (1u << 20));
  u16*   kh   = (u16*)(ws + (2u << 20));
  u16*   kl   = (u16*)(ws + (3u << 20));
  float* nk   = (float*)(ws + (4u << 20));
  float* kkp  = (float*)(ws + (4u << 20) + 32768);
  u32*   cand = (u32*)(ws + (4u << 20) + 65536);
  float* vt   = (float*)(ws + (6u << 20) + 65536);
  size_t need = (8u << 20) + 65536;
  int use_vt = (ws_size >= need) ? 1 : 0;

  prep_kernel<<<use_vt ? 384 : 256, 256, 0, stream>>>(q, k, v, qh, ql, kh, kl, vt, nk);
  kk_kernel<<<32, 256, 0, stream>>>(nk, kkp);
  cost_topk_kernel<<<512, 512, 0, stream>>>(qh, kh, kkp, cand);
  fused_out_kernel<<<512, 1024, 0, stream>>>(qh, ql, kh, kl, kkp, cand, v, vt, out, use_vt);
}

// Round 17
// 56.642 us; speedup vs baseline: 3.6089x; 1.0118x over previous
//
#include <hip/hip_runtime.h>

#define KTOP 8
typedef unsigned short u16;
typedef unsigned int u32;
typedef short bf16x8 __attribute__((ext_vector_type(8)));   // 8 bf16 = 4 VGPR
typedef float f32x16 __attribute__((ext_vector_type(16)));  // 32x32 acc

// ---------- ws byte layout ----------
// qh @0, ql @1M, kh @2M, kl @3M : u16[2*64*4096] each, [b][y][x*64 + (ch^((x&7)<<3))]
// nk @4M (f32 8192)   (kk is now recomputed from nk at use sites)
// cand @4M+64K : u32[2*4096*64]  (2 MB)  quantized keys
// vT   @6M+64K : f32[2*4096*64]  (2 MB)  v transposed [b][pix][ch]  (optional)

__device__ __forceinline__ u16 f2bf(float x) {
  u32 u = __builtin_bit_cast(u32, x);
  u32 r = u + 0x7fffu + ((u >> 16) & 1u);
  return (u16)(r >> 16);
}
__device__ __forceinline__ float bf2f(u16 h) {
  u32 u = ((u32)h) << 16;
  return __builtin_bit_cast(float, u);
}
__device__ __forceinline__ u32 ordenc(float c) {
  u32 u = __builtin_bit_cast(u32, c);
  u32 s = (u32)((int)u >> 31);
  return u ^ (s | 0x80000000u);   // monotone float->uint
}
__device__ __forceinline__ u32 med3u(u32 a, u32 b, u32 c) {
  u32 d;
  asm("v_med3_u32 %0, %1, %2, %3" : "=v"(d) : "v"(a), "v"(b), "v"(c));
  return d;
}
// sorted-ascending top-8 insert: new[0]=min(a0,x), new[p]=med3(a[p-1],a[p],x).
// 8 VALU per candidate, dependency depth 1.
__device__ __forceinline__ void kins(u32 (&k8)[KTOP], u32 x) {
  u32 n0 = k8[0] < x ? k8[0] : x;
#pragma unroll
  for (int p = KTOP - 1; p >= 1; --p) k8[p] = med3u(k8[p - 1], k8[p], x);
  k8[0] = n0;
}

// 3x3 zero-padded stencil of nk at (y,x) — loop order MUST match the old
// kk_kernel (dy outer, dx inner) for bitwise-identical sums.
__device__ __forceinline__ float kk_at(const float* __restrict__ nkb, int y, int x) {
  float s = 0.f;
#pragma unroll
  for (int dy = -1; dy <= 1; ++dy)
#pragma unroll
    for (int dx = -1; dx <= 1; ++dx) {
      int yy = y + dy, xx = x + dx;
      if ((unsigned)yy < 64u && (unsigned)xx < 64u)
        s += nkb[(yy << 6) + xx];
    }
  return s;
}

// ---------------- kernel 1: transpose + bf16 hi/lo split (+ nk) + vT ----------------
__global__ void prep_kernel(const float* __restrict__ q, const float* __restrict__ k,
                            const float* __restrict__ v,
                            u16* __restrict__ qh, u16* __restrict__ ql,
                            u16* __restrict__ kh, u16* __restrict__ kl,
                            float* __restrict__ vt, float* __restrict__ nk) {
  __shared__ float tile[64][65];
  int bid = blockIdx.x;
  int t = threadIdx.x;

  if (bid >= 256) {                       // ---- v transpose path ----
    int r = bid - 256;
    int b = r >> 6, y = r & 63;
    const float* src = v + (size_t)b * (64 * 4096) + (y << 6);
#pragma unroll
    for (int e = 0; e < 16; ++e) {
      int idx = e * 256 + t;
      int c = idx >> 6, x = idx & 63;
      tile[c][x] = src[(c << 12) + x];
    }
    __syncthreads();
    int x = t >> 2, cg = t & 3;
    float* dst = vt + ((size_t)b << 18) + (((y << 6) + x) << 6) + (cg << 4);
#pragma unroll
    for (int i4 = 0; i4 < 4; ++i4) {
      float4 w;
      w.x = tile[cg * 16 + i4 * 4 + 0][x];
      w.y = tile[cg * 16 + i4 * 4 + 1][x];
      w.z = tile[cg * 16 + i4 * 4 + 2][x];
      w.w = tile[cg * 16 + i4 * 4 + 3][x];
      *(float4*)&dst[i4 * 4] = w;
    }
    return;
  }

  int which = bid >> 7;
  int b = (bid >> 6) & 1;
  int y = bid & 63;
  const float* src = (which ? k : q) + (size_t)b * (64 * 4096) + (y << 6);
#pragma unroll
  for (int e = 0; e < 16; ++e) {
    int idx = e * 256 + t;
    int c = idx >> 6, x = idx & 63;
    tile[c][x] = src[(c << 12) + x];
  }
  __syncthreads();

  int x = t >> 2, cg = t & 3;
  u16 hi[16], lo[16];
#pragma unroll
  for (int i = 0; i < 16; ++i) {
    float val = tile[cg * 16 + i][x];
    u16 h = f2bf(val);
    hi[i] = h;
    lo[i] = f2bf(val - bf2f(h));
  }
  u16* dh = (which ? kh : qh) + ((size_t)(b * 64 + y) << 12);
  u16* dl = (which ? kl : ql) + ((size_t)(b * 64 + y) << 12);
  int sw = (x & 7) << 3;
#pragma unroll
  for (int cc = 0; cc < 2; ++cc) {
    int base = (x << 6) + ((cg * 16 + cc * 8) ^ sw);
    uint4 wh, wl;
    wh.x = (u32)hi[cc*8+0] | ((u32)hi[cc*8+1] << 16);
    wh.y = (u32)hi[cc*8+2] | ((u32)hi[cc*8+3] << 16);
    wh.z = (u32)hi[cc*8+4] | ((u32)hi[cc*8+5] << 16);
    wh.w = (u32)hi[cc*8+6] | ((u32)hi[cc*8+7] << 16);
    wl.x = (u32)lo[cc*8+0] | ((u32)lo[cc*8+1] << 16);
    wl.y = (u32)lo[cc*8+2] | ((u32)lo[cc*8+3] << 16);
    wl.z = (u32)lo[cc*8+4] | ((u32)lo[cc*8+5] << 16);
    wl.w = (u32)lo[cc*8+6] | ((u32)lo[cc*8+7] << 16);
    *(uint4*)&dh[base] = wh;
    *(uint4*)&dl[base] = wl;
  }
  if (which && t < 64) {
    float s = 0.f;
#pragma unroll
    for (int c = 0; c < 64; ++c) { float vv = tile[c][t]; s += vv * vv; }
    nk[(b << 12) + (y << 6) + t] = s;
  }
}

// ---------------- kernel 2: ring + hi-only MFMA cost + med3 top-8 ----------------
// grid 512 = b(2) x rowpair(32) x eighth(8); block 512; 2 blocks/CU.
// MFMA split into 2 independent acc chains + s_setprio around MFMA cluster.
__launch_bounds__(512, 4)
__global__ void cost_topk_kernel(const u16* __restrict__ qh,
                                 const u16* __restrict__ kh,
                                 const float* __restrict__ nkg,
                                 u32* __restrict__ cand) {
  __shared__ __align__(16) u16 ring[4][4096];        // 32 KB, slot = row & 3
  __shared__ float RbBuf[2 * 66 * 67 + 4];           // 2 bordered S tiles
  __shared__ float kkbuf[512];                       // kk rows q0..q0+7

  int bid = blockIdx.x;
  int b   = bid >> 8;
  int rp  = (bid >> 3) & 31;
  int e8  = bid & 7;
  int q0  = e8 << 3;
  int iy0 = rp << 1;

  int t = threadIdx.x;
  int lane = t & 63;
  int wv = t >> 6;
  int h  = wv >> 2;
  int quad = wv & 3;
  int wr = quad >> 1, wc = quad & 1;
  int l31 = lane & 31, lk8 = (lane >> 5) << 3;
  int apix = (wr << 5) + l31;
  int bpix = (wc << 5) + l31;
  int sx = t & 63, sseg = (t >> 6) & 3, jxs = sseg << 4;
  int iy = iy0 + h;

  const u16* qhb = qh + ((size_t)b << 18);
  const u16* khb = kh + ((size_t)b << 18);
  const float* nkb = nkg + ((size_t)b << 12);

  const bf16x8 z8 = {0,0,0,0,0,0,0,0};
  const uint4 z4 = {0u,0u,0u,0u};

  // A fragments (hi only), rows iy-1..iy+1, direct global->VGPR
  bf16x8 qa[3][4];
  int swA = (apix & 7) << 3;
#pragma unroll
  for (int d = 0; d < 3; ++d) {
    int qy = iy - 1 + d;
    bool ok = (unsigned)qy < 64u;
    int rb = (qy & 63) << 12;
#pragma unroll
    for (int c4 = 0; c4 < 4; ++c4) {
      bf16x8 vv = *(const bf16x8*)&qhb[rb + (apix << 6) + (((c4 << 4) + lk8) ^ swA)];
      qa[d][c4] = ok ? vv : z8;
    }
  }

  // zero Rb (borders stay zero); compute kk rows q0..q0+7 from nk (fused);
  // prefill ring rows q0-1..q0+1
  for (int i = t; i < 2 * 66 * 67 + 4; i += 512) RbBuf[i] = 0.f;
  kkbuf[t] = kk_at(nkb, q0 + (t >> 6), t & 63);
#pragma unroll
  for (int d = 0; d < 3; ++d) {
    int r = q0 - 1 + d;
    bool ok = (unsigned)r < 64u;
    uint4 vv = ok ? *(const uint4*)&khb[((r & 63) << 12) + (t << 3)] : z4;
    *(uint4*)&ring[(r + 4) & 3][t << 3] = vv;
  }
  __syncthreads();

  u32 k8a[KTOP], k8b[KTOP];
#pragma unroll
  for (int s = 0; s < KTOP; ++s) { k8a[s] = 0xFFFFFFFFu; k8b[s] = 0xFFFFFFFFu; }

  int swB = (bpix & 7) << 3;
  float* Rh = &RbBuf[h * (66 * 67)];

  for (int jt = 0; jt < 8; ++jt) {
    int jy = q0 + jt;
    // prefetch next ring row (global->reg; LDS write after barrier)
    int pr = jy + 2;
    bool pok = (jt < 7) && (pr < 64);
    uint4 pf = pok ? *(const uint4*)&khb[((pr & 63) << 12) + (t << 3)] : z4;

    // ---- MFMA: two independent acc chains (halve dependent-MFMA latency) ----
    f32x16 acc0, acc1;
#pragma unroll
    for (int i = 0; i < 16; ++i) { acc0[i] = 0.f; acc1[i] = 0.f; }
    __builtin_amdgcn_s_setprio(1);
#pragma unroll
    for (int d = 0; d < 3; ++d) {
      const u16* rg = ring[(jy - 1 + d) & 3];
#pragma unroll
      for (int c4 = 0; c4 < 4; ++c4) {
        bf16x8 bh = *(const bf16x8*)&rg[(bpix << 6) + (((c4 << 4) + lk8) ^ swB)];
        if ((d ^ c4) & 1)
          acc1 = __builtin_amdgcn_mfma_f32_32x32x16_bf16(qa[d][c4], bh, acc1, 0, 0, 0);
        else
          acc0 = __builtin_amdgcn_mfma_f32_32x32x16_bf16(qa[d][c4], bh, acc0, 0, 0, 0);
      }
    }
    __builtin_amdgcn_s_setprio(0);
    __syncthreads();   // prev stencil reads of Rb done (ring write slot disjoint)

    // C-write (col=lane&31, row=(r&3)+8*(r>>2)+4*(lane>>5)) into bordered tile
#pragma unroll
    for (int r = 0; r < 16; ++r) {
      int row = (wr << 5) + (r & 3) + ((r >> 2) << 3) + ((lane >> 5) << 2);
      Rh[(row + 1) * 67 + (wc << 5) + l31 + 1] = acc0[r] + acc1[r];
    }
    if (jt < 7) *(uint4*)&ring[pr & 3][t << 3] = pf;
    __syncthreads();   // S + ring row visible

    // diagonal 3-point stencil + cost + 2-chain med3 top-8
    float a16[16];
    {
      const float* rm = &Rh[sx * 67 + jxs];
      const float* rc = &Rh[(sx + 1) * 67 + jxs];
      const float* rq = &Rh[(sx + 2) * 67 + jxs];
#pragma unroll
      for (int jj = 0; jj < 16; ++jj)
        a16[jj] = rm[jj] + rc[jj + 1] + rq[jj + 2];
    }
    const float* kkr = &kkbuf[(jt << 6) + jxs];
    int jbase = (jy << 6) + jxs;
#pragma unroll
    for (int jj = 0; jj < 16; ++jj) {
      float cost = kkr[jj] - 2.f * a16[jj];
      u32 key = (ordenc(cost) & 0xFFFFF000u) | (u32)(jbase + jj);
      if (jj & 1) kins(k8b, key); else kins(k8a, key);
    }
  }

#pragma unroll
  for (int s = 0; s < KTOP; ++s) kins(k8a, k8b[s]);

  // block merge: 4 segments per query -> per-eighth top-8
  __syncthreads();
  u32* lbuf = (u32*)ring;   // 128 queries x 32 keys = 16 KB
  int qloc = (h << 6) + sx;
#pragma unroll
  for (int s = 0; s < KTOP; ++s) lbuf[(qloc << 5) + (sseg << 3) + s] = k8a[s];
  __syncthreads();
  if (t < 128) {
    u32 m8a[KTOP], m8b[KTOP];
#pragma unroll
    for (int s = 0; s < KTOP; ++s) { m8a[s] = 0xFFFFFFFFu; m8b[s] = 0xFFFFFFFFu; }
    const u32* lp = &lbuf[t << 5];
#pragma unroll
    for (int e = 0; e < 16; ++e) {
      kins(m8a, lp[e * 2]);
      kins(m8b, lp[e * 2 + 1]);
    }
#pragma unroll
    for (int s = 0; s < KTOP; ++s) kins(m8a, m8b[s]);
    int qi = ((iy0 + (t >> 6)) << 6) + (t & 63);
    u32* dst = cand + (((size_t)(b << 12) + qi) << 6) + (e8 << 3);
#pragma unroll
    for (int s = 0; s < KTOP; ++s) dst[s] = m8a[s];
  }
}

// ---------------- kernel 3 (fused): bitonic merge + hi/lo rescore + softmax + gather ----
__launch_bounds__(1024)
__global__ void fused_out_kernel(const u16* __restrict__ qh, const u16* __restrict__ ql,
                                 const u16* __restrict__ kh, const u16* __restrict__ kl,
                                 const float* __restrict__ nkg, const u32* __restrict__ cand,
                                 const float* __restrict__ v, const float* __restrict__ vt,
                                 float* __restrict__ out, int use_vt) {
  __shared__ float otile[64 * 17];
  int t = threadIdx.x;
  int wid = t >> 6, lane = t & 63;
  int qi = blockIdx.x * 16 + wid;          // == (b<<12) + qpix
  int b = qi >> 12, qpix = qi & 4095;

  // ---- phase A: 64-lane bitonic sort of this query's 64 candidate keys ----
  u32 key = cand[((size_t)qi << 6) + lane];
#pragma unroll
  for (int kk2 = 2; kk2 <= 64; kk2 <<= 1) {
#pragma unroll
    for (int j2 = kk2 >> 1; j2 > 0; j2 >>= 1) {
      u32 o = (u32)__shfl_xor((int)key, j2);
      bool up = ((lane & kk2) == 0);
      bool lowr = ((lane & j2) == 0);
      u32 mn = key < o ? key : o;
      u32 mx = key < o ? o : key;
      key = (up == lowr) ? mn : mx;
    }
  }

  // ---- phase B: hi/lo rescore; slot s = lane>>3, ch group g = lane&7 ----
  int s = lane >> 3, g = lane & 7;
  int j = (u32)__shfl((int)key, s) & 0xFFFu;
  int yi = qpix >> 6, xi = qpix & 63;
  int yj = j >> 6, xj = j & 63;
  const u16* qhb = qh + ((size_t)b << 18);
  const u16* qlb = ql + ((size_t)b << 18);
  const u16* khb = kh + ((size_t)b << 18);
  const u16* klb = kl + ((size_t)b << 18);

  float dot = 0.f;
#pragma unroll
  for (int di = 0; di < 3; ++di) {
    int qy = yi + di - 1, ky = yj + di - 1;
    bool vy = ((unsigned)qy < 64u) && ((unsigned)ky < 64u);
#pragma unroll
    for (int dj = 0; dj < 3; ++dj) {
      int qx = xi + dj - 1, kx = xj + dj - 1;
      bool ok = vy && ((unsigned)qx < 64u) && ((unsigned)kx < 64u);
      int qxc = qx & 63, kxc = kx & 63;
      int qa = ((qy & 63) << 12) + (qxc << 6) + ((g << 3) ^ ((qxc & 7) << 3));
      int ka = ((ky & 63) << 12) + (kxc << 6) + ((g << 3) ^ ((kxc & 7) << 3));
      uint4 aqh = *(const uint4*)&qhb[qa];
      uint4 aql = *(const uint4*)&qlb[qa];
      uint4 akh = *(const uint4*)&khb[ka];
      uint4 akl = *(const uint4*)&klb[ka];
      const u32* wqh = (const u32*)&aqh;
      const u32* wql = (const u32*)&aql;
      const u32* wkh = (const u32*)&akh;
      const u32* wkl = (const u32*)&akl;
      float pacc = 0.f;
#pragma unroll
      for (int e = 0; e < 4; ++e) {
        float q0 = __builtin_bit_cast(float, wqh[e] << 16) +
                   __builtin_bit_cast(float, wql[e] << 16);
        float q1 = __builtin_bit_cast(float, wqh[e] & 0xFFFF0000u) +
                   __builtin_bit_cast(float, wql[e] & 0xFFFF0000u);
        float k0 = __builtin_bit_cast(float, wkh[e] << 16) +
                   __builtin_bit_cast(float, wkl[e] << 16);
        float k1 = __builtin_bit_cast(float, wkh[e] & 0xFFFF0000u) +
                   __builtin_bit_cast(float, wkl[e] & 0xFFFF0000u);
        pacc = fmaf(q0, k0, pacc);
        pacc = fmaf(q1, k1, pacc);
      }
      dot += ok ? pacc : 0.f;
    }
  }
#pragma unroll
  for (int off = 1; off < 8; off <<= 1) dot += __shfl_xor(dot, off);

  // kk[j] recomputed from nk (bitwise-identical loop order to old kk_kernel);
  // uniform within each 8-lane slot group -> coalesced, L1/L2-hot
  float kkj = kk_at(nkg + ((size_t)b << 12), yj, xj);
  float cost = kkj - 2.f * dot;

  // ---- phase C: softmax over the 8 slots ----
  float m = cost;
#pragma unroll
  for (int off = 8; off < 64; off <<= 1) m = fminf(m, __shfl_xor(m, off));
  float w = __expf(m - cost);
  float wsum = w;
#pragma unroll
  for (int off = 8; off < 64; off <<= 1) wsum += __shfl_xor(wsum, off);
  w /= wsum;

  // ---- phase D: gather v, channel per lane ----
  float wk2[8]; int jk[8];
#pragma unroll
  for (int ss = 0; ss < 8; ++ss) {
    wk2[ss] = __shfl(w, ss << 3);
    jk[ss]  = __shfl(j, ss << 3);
  }
  float acc = 0.f;
  if (use_vt) {
    const float* vtb = vt + ((size_t)b << 18);
#pragma unroll
    for (int ss = 0; ss < 8; ++ss) acc += wk2[ss] * vtb[(jk[ss] << 6) + lane];
  } else {
    const float* vb = v + ((size_t)b << 18);
#pragma unroll
    for (int ss = 0; ss < 8; ++ss) acc += wk2[ss] * vb[(lane << 12) + jk[ss]];
  }
  otile[lane * 17 + wid] = acc;
  __syncthreads();

  int c2 = t >> 4, qq = t & 15;
  int pixbase = (blockIdx.x & 255) << 4;
  out[((size_t)b << 18) + (c2 << 12) + pixbase + qq] = otile[c2 * 17 + qq];
}

extern "C" void kernel_launch(void* const* d_in, const int* in_sizes, int n_in,
                              void* d_out, int out_size, void* d_ws, size_t ws_size,
                              hipStream_t stream) {
  const float* q = (const float*)d_in[0];
  const float* k = (const float*)d_in[1];
  const float* v = (const float*)d_in[2];
  float* out = (float*)d_out;

  char* ws = (char*)d_ws;
  u16*   qh   = (u16*)(ws);
  u16*   ql   = (u16*)(ws + (1u << 20));
  u16*   kh   = (u16*)(ws + (2u << 20));
  u16*   kl   = (u16*)(ws + (3u << 20));
  float* nk   = (float*)(ws + (4u << 20));
  u32*   cand = (u32*)(ws + (4u << 20) + 65536);
  float* vt   = (float*)(ws + (6u << 20) + 65536);
  size_t need = (8u << 20) + 65536;
  int use_vt = (ws_size >= need) ? 1 : 0;

  prep_kernel<<<use_vt ? 384 : 256, 256, 0, stream>>>(q, k, v, qh, ql, kh, kl, vt, nk);
  cost_topk_kernel<<<512, 512, 0, stream>>>(qh, kh, nk, cand);
  fused_out_kernel<<<512, 1024, 0, stream>>>(qh, ql, kh, kl, nk, cand, v, vt, out, use_vt);
}